// Round 22
// baseline (565.191 us; speedup 1.0000x reference)
//
#include <hip/hip_runtime.h>

#define BS 16
#define NH 16
#define LQ 4096
#define DH 32

constexpr size_t OUT_ELEMS = (size_t)BS * NH * LQ * DH;   // 33,554,432
constexpr int HDE = NH * DH * DH;           // 16384

__device__ __forceinline__ void fma4(float4& a, float s, const float4& v) {
    a.x = fmaf(s, v.x, a.x);
    a.y = fmaf(s, v.y, a.y);
    a.z = fmaf(s, v.z, a.z);
    a.w = fmaf(s, v.w, a.w);
}

// ---------------- Kernel A: partial K@V — scalar-pipe K, zero-sync ----------------
// 9 structural families (R2-R21) all plateau 95-105us: any wave-SHARED operand
// distribution (LDS or L1-broadcast) stalls ~85%. New family: make K[d][s]
// WAVE-UNIFORM. 64-thread blocks (1 wave; task = blockIdx only -> provably
// uniform addresses -> hipcc emits s_load for K). Lane = e-column; acc[32] =
// full d-column of W. K: s_load_dwordx4 from one SGPR base + imm offsets --
// scalar pipe + scalar cache, ZERO VALU/L1-vector/LDS cost. V: 1 coalesced
// vector load per s (128B distinct, every line consumed once -- the R18-probe
// pattern). FMA: v_fmac acc, sK, vV (1 SGPR operand, legal). Accepted cost:
// lanes 32-63 duplicate 0-31 (uniformity forces <=32 useful lanes) -> VALU
// floor 27us. NO LDS, NO barriers, NO sync at all. 16 waves/CU (4096 blocks).
template<int SCHUNK>
__global__ __launch_bounds__(64) void kv_partial(const float* __restrict__ k,
                                                 const float* __restrict__ v,
                                                 float* __restrict__ part) {
    const int l  = threadIdx.x;
    const int e  = l & 31;
    const int nsplit = LQ / SCHUNK;
    const int p  = blockIdx.x % nsplit;     // blockIdx-only -> uniform K base
    const int bh = blockIdx.x / nsplit;

    const float* kb = k + (size_t)bh * DH * LQ + p * SCHUNK;          // uniform
    const float* vb = v + ((size_t)bh * LQ + (size_t)p * SCHUNK) * DH + e;

    float acc[32];
#pragma unroll
    for (int d = 0; d < 32; ++d) acc[d] = 0.f;

#pragma unroll 2
    for (int s = 0; s < SCHUNK; s += 4) {
        // K window: 32 rows x 4 s. Uniform addr (kb uniform, d/s constants
        // after unroll) -> s_load_dwordx4, values live in SGPRs.
        float4 kw[32];
#pragma unroll
        for (int d = 0; d < 32; ++d)
            kw[d] = *(const float4*)(kb + (size_t)d * LQ + s);
        // V: lane's own column, 1 coalesced instr per s (128 B distinct).
        float v0 = vb[(size_t)(s + 0) * DH];
        float v1 = vb[(size_t)(s + 1) * DH];
        float v2 = vb[(size_t)(s + 2) * DH];
        float v3 = vb[(size_t)(s + 3) * DH];
#pragma unroll
        for (int d = 0; d < 32; ++d) acc[d] = fmaf(kw[d].x, v0, acc[d]);
#pragma unroll
        for (int d = 0; d < 32; ++d) acc[d] = fmaf(kw[d].y, v1, acc[d]);
#pragma unroll
        for (int d = 0; d < 32; ++d) acc[d] = fmaf(kw[d].z, v2, acc[d]);
#pragma unroll
        for (int d = 0; d < 32; ++d) acc[d] = fmaf(kw[d].w, v3, acc[d]);
    }

    // store: lanes 0-31 (upper half is the uniformity-duplicate). Per d:
    // 32 lanes x 4 B = 128 B contiguous -> coalesced.
    if (l < 32) {
        float* pb = part + ((size_t)p * (BS * NH) + bh) * 1024 + e;
#pragma unroll
        for (int d = 0; d < 32; ++d) pb[d * 32] = acc[d];
    }
}

// ---------------- Kernel B1: reduce partials over p (R12-proven) ----------------
__global__ __launch_bounds__(256) void reduce_p(const float* __restrict__ part,
                                                float* __restrict__ wts, int nsp) {
    const int gidx = blockIdx.x * 256 + threadIdx.x;   // b*16384 + h*1024+d*32+e
    float s = 0.f;
#pragma unroll 8
    for (int pp = 0; pp < nsp; ++pp)
        s += part[((size_t)pp << 18) + gidx];
    wts[gidx] = s * (1.0f / 64.0f);                    // / sqrt(4096)
}

// ---------------- Kernel B2: softmax over batch axis (R12-proven) ----------------
__global__ __launch_bounds__(256) void softmax_b(float* __restrict__ wts) {
    const int idx = blockIdx.x * 256 + threadIdx.x;    // 0..16383

    float sc[BS];
#pragma unroll
    for (int b = 0; b < BS; ++b) sc[b] = wts[((size_t)b << 14) + idx];
    float m = sc[0];
#pragma unroll
    for (int b = 1; b < BS; ++b) m = fmaxf(m, sc[b]);
    float sum = 0.f;
#pragma unroll
    for (int b = 0; b < BS; ++b) { sc[b] = __expf(sc[b] - m); sum += sc[b]; }
    const float inv = 1.0f / sum;
#pragma unroll
    for (int b = 0; b < BS; ++b) wts[((size_t)b << 14) + idx] = sc[b] * inv;
}

// ---------------- Kernel C: out = Q @ W (R12-proven, ~26us) ----------------
__global__ __launch_bounds__(256, 2) void qw(const float* __restrict__ q,
                                             const float* __restrict__ wts,
                                             float* __restrict__ out) {
    __shared__ float qs[128 * 36];
    const int blk = blockIdx.x;
    const int bh  = blk >> 5;
    const int lt  = blk & 31;
    const int tid = threadIdx.x;

    const float* qbase = q + ((size_t)bh * LQ + lt * 128) * DH;

#pragma unroll
    for (int pp = 0; pp < 4; ++pp) {
        const int idx = pp * 256 + tid;           // float4 index 0..1023
        const int row = idx >> 3;
        const int c4  = idx & 7;
        const float4 t = *(const float4*)(qbase + idx * 4);
        *(float4*)(qs + row * 36 + c4 * 4) = t;
    }

    const int lsub = tid >> 3;                    // 0..31
    const int e0   = (tid & 7) << 2;

    // wts layout [b][h][d][e]: base = b*16384 + h*1024
    const int b = bh >> 4, h = bh & 15;
    float4 Wf[32];
    const float* wbase = wts + ((size_t)b << 14) + ((size_t)h << 10) + e0;
#pragma unroll
    for (int d = 0; d < 32; ++d) Wf[d] = *(const float4*)(wbase + d * DH);

    __syncthreads();

    float* obase = out + ((size_t)bh * LQ + lt * 128) * DH;

#pragma unroll
    for (int r = 0; r < 4; ++r) {
        const int lr = lsub + r * 32;
        const float* qrow = qs + lr * 36;
        float4 acc = {0, 0, 0, 0};
#pragma unroll
        for (int d4 = 0; d4 < 32; d4 += 4) {
            const float4 qv = *(const float4*)(qrow + d4);
            fma4(acc, qv.x, Wf[d4 + 0]);
            fma4(acc, qv.y, Wf[d4 + 1]);
            fma4(acc, qv.z, Wf[d4 + 2]);
            fma4(acc, qv.w, Wf[d4 + 3]);
        }
        *(float4*)(obase + (size_t)lr * DH + e0) = acc;
    }
}

extern "C" void kernel_launch(void* const* d_in, const int* in_sizes, int n_in,
                              void* d_out, int out_size, void* d_ws, size_t ws_size,
                              hipStream_t stream) {
    const float* q = (const float*)d_in[0];
    const float* k = (const float*)d_in[1];
    const float* v = (const float*)d_in[2];
    float* out  = (float*)d_out;
    float* wts  = out + OUT_ELEMS;          // attn_weights region of d_out
    float* part = (float*)d_ws;

    const size_t need16 = (size_t)16 * 256 * 1024 * 4;   // 16.8 MB of partials
    int nsp;
    if (ws_size >= need16) {
        kv_partial<256><<<256 * 16, 64, 0, stream>>>(k, v, part);   // 4096 waves
        nsp = 16;
    } else {
        kv_partial<512><<<256 * 8, 64, 0, stream>>>(k, v, part);    // 2048 waves
        nsp = 8;
    }
    reduce_p<<<(BS * HDE) / 256, 256, 0, stream>>>(part, wts, nsp);
    softmax_b<<<HDE / 256, 256, 0, stream>>>(wts);
    qw<<<BS * NH * (LQ / 128), 256, 0, stream>>>(q, wts, out);
}